// Round 6
// baseline (146.598 us; speedup 1.0000x reference)
//
#include <hip/hip_runtime.h>
#include <hip/hip_bf16.h>

typedef __attribute__((ext_vector_type(4))) float f32x4;
typedef __attribute__((ext_vector_type(8))) short short8;

#define B_ 16
#define C_ 64
#define H_ 128
#define W_ 128
#define Z_ 128
#define HW_ (H_*W_)
#define CHW_ (C_*H_*W_)
#define IDXN (C_*C_*9)    // 36864 weight elements per sample
#define NT 18             // K=576 -> 18 MFMA k-steps of 32

__device__ __forceinline__ unsigned short f2bf(float f) {
  __hip_bfloat16 h = __float2bfloat16(f);
  return *reinterpret_cast<unsigned short*>(&h);
}

// ---------------- kernel 1: weight generation, pre-swizzled to MFMA fragment layout
__global__ __launch_bounds__(256) void wgen_k(
    const float* __restrict__ z, const float* __restrict__ gw,
    const float* __restrict__ gb, unsigned short* __restrict__ wfrag) {
  __shared__ __align__(16) float zs[B_*Z_];   // 8 KB
  int t = threadIdx.x;
#pragma unroll
  for (int i = 0; i < 8; ++i) zs[i*256 + t] = z[i*256 + t];
  __syncthreads();
  int lane = t & 63, bg = t >> 6;
  int b0 = bg*4;
  int idx0 = blockIdx.x*128 + lane;           // stream 0: idx0, stream 1: idx0+64
  float acc[4][2];
  float bv0 = gb[idx0], bv1 = gb[idx0 + 64];
#pragma unroll
  for (int bi = 0; bi < 4; ++bi) { acc[bi][0] = bv0; acc[bi][1] = bv1; }

  for (int z0 = 0; z0 < Z_; z0 += 4) {
    float ga[4], gbv[4];
#pragma unroll
    for (int zi = 0; zi < 4; ++zi) {
      ga[zi]  = gw[(size_t)(z0+zi)*IDXN + idx0];
      gbv[zi] = gw[(size_t)(z0+zi)*IDXN + idx0 + 64];
    }
#pragma unroll
    for (int bi = 0; bi < 4; ++bi) {
      f32x4 zq = *reinterpret_cast<const f32x4*>(&zs[(b0+bi)*Z_ + z0]);
      acc[bi][0] = fmaf(zq[0], ga[0], fmaf(zq[1], ga[1], fmaf(zq[2], ga[2], fmaf(zq[3], ga[3], acc[bi][0]))));
      acc[bi][1] = fmaf(zq[0], gbv[0], fmaf(zq[1], gbv[1], fmaf(zq[2], gbv[2], fmaf(zq[3], gbv[3], acc[bi][1]))));
    }
  }
#pragma unroll
  for (int ni = 0; ni < 2; ++ni) {
    int idx = idx0 + ni*64;
    int kw = idx % 3, r1 = idx/3;
    int kh = r1 % 3, r2 = r1/3;
    int ci = r2 & 63, co = r2 >> 6;
    int k = (kh*3 + kw)*C_ + ci;
    int ts = k >> 5, kin = k & 31;
    int lm = (co & 15) | ((kin >> 3) << 4);
    int j = kin & 7, m = co >> 4;
    int base = ((ts*4 + m)*64 + lm)*8 + j;
#pragma unroll
    for (int bi = 0; bi < 4; ++bi)
      wfrag[(size_t)(b0+bi)*(NT*4*64*8) + base] = f2bf(acc[bi][ni]);
  }
}

// ---------------- kernel 2: persistent-band conv, 6-slot LDS ring, T14 staged overlap
// grid 256 (1 block/CU), 1024 thr = 16 waves. Block: sample b, 8-row band (4 pairs).
// LDS ring: xs[6 slots][130 cols][8 chunk-slots][16B]; slot(img row g) = (g+1)%6.
// Content: slot s at col holds ci-chunk s^(col&7) (XOR swizzle, verified).
// Wave v: row phr=v>>3, px-quarter pw0=((v>>1)&3)*32 (mp=2 x 16px), co-half mt0=(v&1)*2 (nc=2).
__global__ __launch_bounds__(1024, 4) void conv_k(
    const float* __restrict__ x,
    const unsigned short* __restrict__ wfrag,
    float* __restrict__ out) {
  __shared__ __align__(16) unsigned char xs[6*130*128];   // 99840 B -> 1 block/CU
  int orig = blockIdx.x;
  int blk = (orig & 7)*32 + (orig >> 3);   // bijective XCD swizzle: 256 = 8*32
  int b = blk >> 4;
  int band = blk & 15;
  int hbase = band*8;
  int tid = threadIdx.x;
  int v = tid >> 6, lane = tid & 63;

  // staging coords: thread stages chunk cig at w-pair wp of row (pass base + ri)
  int ri = tid >> 9;          // 0/1
  int wp = lane;              // 0..63
  int cig = v & 7;            // ci-chunk 0..7 (wave-uniform)
  const float* xb = x + (size_t)b*CHW_;
  int s_base0 = hbase % 6;

  // zero pad cols 0 and 129 of all 6 slots (never touched by staging)
  if (tid < 96) {
    int sl = tid >> 4, cc = (tid >> 3) & 1, ch = tid & 7;
    int col = cc ? 129 : 0;
    uint4 zv; zv.x = 0; zv.y = 0; zv.z = 0; zv.w = 0;
    *reinterpret_cast<uint4*>(&xs[(sl*130 + col)*128 + ch*16]) = zv;
  }

  // prologue: stage passes 0,1 = image rows hbase-1 .. hbase+2
#pragma unroll
  for (int s = 0; s < 2; ++s) {
    int g = hbase - 1 + 2*s + ri;
    int slw = s_base0 + 2*s + ri; if (slw >= 6) slw -= 6;   // (g+1)%6
    uint4 o0, o1;
    o0.x=0;o0.y=0;o0.z=0;o0.w=0; o1=o0;
    if (g >= 0 && g < H_) {
      const float* xr = xb + (size_t)g*W_ + 2*wp;
      unsigned short* p0 = reinterpret_cast<unsigned short*>(&o0);
      unsigned short* p1 = reinterpret_cast<unsigned short*>(&o1);
#pragma unroll
      for (int j = 0; j < 8; ++j) {
        float2 f = *reinterpret_cast<const float2*>(xr + (size_t)(cig*8 + j)*HW_);
        p0[j] = f2bf(f.x); p1[j] = f2bf(f.y);
      }
    }
    int c0 = 2*wp + 1, c1 = c0 + 1;
    *reinterpret_cast<uint4*>(&xs[(slw*130 + c0)*128 + (((cig ^ c0) & 7) << 4)]) = o0;
    *reinterpret_cast<uint4*>(&xs[(slw*130 + c1)*128 + (((cig ^ c1) & 7) << 4)]) = o1;
  }
  __syncthreads();

  int l15 = lane & 15, lhi = lane >> 4;
  int phr = v >> 3;
  int pw0 = ((v >> 1) & 3) * 32;
  int mt0 = (v & 1) * 2;
  const unsigned short* wb = wfrag + (size_t)b*(NT*4*64*8);

  int s_base = s_base0;                  // (hbase + 2p) % 6
  float2 sv[8];

#pragma unroll 1
  for (int p = 0; p < 4; ++p) {
    // ---- part A: ISSUE stage loads for pass p+2 (rows hbase+2p+3, +4); latency hides under K-loop
    int sg = hbase + 2*p + 3 + ri;
    bool sval = (p < 3) && (sg < H_);
    if (sval) {
      const float* xr = xb + (size_t)sg*W_ + 2*wp;
#pragma unroll
      for (int j = 0; j < 8; ++j)
        sv[j] = *reinterpret_cast<const float2*>(xr + (size_t)(cig*8 + j)*HW_);
    }

    // ---- K-loop for pair p (reads ring slots s_base .. s_base+3 mod 6)
    f32x4 acc[2][2];
#pragma unroll
    for (int mp = 0; mp < 2; ++mp)
#pragma unroll
      for (int nc = 0; nc < 2; ++nc)
        acc[mp][nc] = (f32x4){0.f, 0.f, 0.f, 0.f};

    short8 xa0[2], xa1[2], wf0[2], wf1[2];
    {   // t = 0 prefetch (kh=0, kw=0, half=0)
      int chunk = lhi;
      int rs = s_base + phr; if (rs >= 6) rs -= 6;
#pragma unroll
      for (int mp = 0; mp < 2; ++mp) {
        int col = pw0 + mp*16 + l15;
        xa0[mp] = *reinterpret_cast<const short8*>(&xs[(rs*130 + col)*128 + (((chunk ^ col) & 7) << 4)]);
      }
#pragma unroll
      for (int nc = 0; nc < 2; ++nc)
        wf0[nc] = *reinterpret_cast<const short8*>(wb + ((mt0 + nc)*64 + lane)*8);
    }
#pragma unroll
    for (int t = 0; t < NT; ++t) {
      if (t + 1 < NT) {                  // prefetch t+1 (LDS + weights) before t's MFMAs
        int t1 = t + 1;
        int kk = t1 >> 1, kh = kk/3, kw = kk%3, half = t1 & 1;
        int chunk = half*4 + lhi;
        int rs = s_base + phr + kh; if (rs >= 6) rs -= 6;
#pragma unroll
        for (int mp = 0; mp < 2; ++mp) {
          int col = pw0 + mp*16 + l15 + kw;
          xa1[mp] = *reinterpret_cast<const short8*>(&xs[(rs*130 + col)*128 + (((chunk ^ col) & 7) << 4)]);
        }
#pragma unroll
        for (int nc = 0; nc < 2; ++nc)
          wf1[nc] = *reinterpret_cast<const short8*>(wb + ((t1*4 + mt0 + nc)*64 + lane)*8);
      }
#pragma unroll
      for (int mp = 0; mp < 2; ++mp)
#pragma unroll
        for (int nc = 0; nc < 2; ++nc)
          acc[mp][nc] = __builtin_amdgcn_mfma_f32_16x16x32_bf16(xa0[mp], wf0[nc], acc[mp][nc], 0, 0, 0);
      xa0[0] = xa1[0]; xa0[1] = xa1[1];
      wf0[0] = wf1[0]; wf0[1] = wf1[1];
    }

    // ---- epilogue pair p: D row=(lane>>4)*4+i -> pixel (f32x4), col=lane&15 -> co
    int ph = hbase + 2*p + phr;
#pragma unroll
    for (int nc = 0; nc < 2; ++nc) {
      int co = (mt0 + nc)*16 + l15;
      float* op = out + (((size_t)b*C_ + co)*H_ + ph)*W_;
#pragma unroll
      for (int mp = 0; mp < 2; ++mp)
        *reinterpret_cast<f32x4*>(op + pw0 + mp*16 + lhi*4) = acc[mp][nc];
    }

    // ---- part B: commit staged rows into ring slots (s_base+4, s_base+5 mod 6)
    // (disjoint from pair p's read slots -> safe without extra barrier)
    if (p < 3) {
      int slw = s_base + 4 + ri; if (slw >= 6) slw -= 6;
      uint4 o0, o1;
      o0.x=0;o0.y=0;o0.z=0;o0.w=0; o1=o0;
      if (sval) {
        unsigned short* p0 = reinterpret_cast<unsigned short*>(&o0);
        unsigned short* p1 = reinterpret_cast<unsigned short*>(&o1);
#pragma unroll
        for (int j = 0; j < 8; ++j) { p0[j] = f2bf(sv[j].x); p1[j] = f2bf(sv[j].y); }
      }
      int c0 = 2*wp + 1, c1 = c0 + 1;
      *reinterpret_cast<uint4*>(&xs[(slw*130 + c0)*128 + (((cig ^ c0) & 7) << 4)]) = o0;
      *reinterpret_cast<uint4*>(&xs[(slw*130 + c1)*128 + (((cig ^ c1) & 7) << 4)]) = o1;
    }
    s_base += 2; if (s_base >= 6) s_base -= 6;
    __syncthreads();
  }
}

__global__ void sentinel_k(float* out, int n) {
  int i = blockIdx.x*256 + threadIdx.x;
  if (i < n) out[i] = 1.0e6f;
}

extern "C" void kernel_launch(void* const* d_in, const int* in_sizes, int n_in,
                              void* d_out, int out_size, void* d_ws, size_t ws_size,
                              hipStream_t stream) {
  const float* x  = (const float*)d_in[0];
  const float* z  = (const float*)d_in[1];
  const float* gw = (const float*)d_in[2];
  const float* gb = (const float*)d_in[3];
  float* out = (float*)d_out;

  size_t wfrag_elems = (size_t)B_*IDXN;                   // bf16 elems
  size_t need = wfrag_elems*sizeof(unsigned short);
  if (ws_size < need) {
    sentinel_k<<<(out_size + 255)/256, 256, 0, stream>>>(out, out_size);
    return;
  }
  unsigned short* wfrag = (unsigned short*)d_ws;

  wgen_k <<<IDXN/128, 256, 0, stream>>>(z, gw, gb, wfrag);
  conv_k <<<B_*16, 1024, 0, stream>>>(x, wfrag, out);
}

// Round 7
// 52.449 us; speedup vs baseline: 2.7951x; 2.7951x over previous
//
#include <hip/hip_runtime.h>
#include <hip/hip_bf16.h>

typedef __attribute__((ext_vector_type(4))) float f32x4;
typedef __attribute__((ext_vector_type(8))) short short8;

#define B_ 16
#define C_ 64
#define H_ 128
#define W_ 128
#define Z_ 128
#define IDXN (C_*C_*9)    // 36864 weight elements per sample
#define NT 18             // K=576 -> 18 MFMA k-steps of 32

__device__ __forceinline__ unsigned short f2bf(float f) {
  __hip_bfloat16 h = __float2bfloat16(f);
  return *reinterpret_cast<unsigned short*>(&h);
}

// ---------------- kernel 1: weight generation, pre-swizzled to MFMA fragment layout
__global__ __launch_bounds__(256) void wgen_k(
    const float* __restrict__ z, const float* __restrict__ gw,
    const float* __restrict__ gb, unsigned short* __restrict__ wfrag) {
  __shared__ __align__(16) float zs[B_*Z_];   // 8 KB
  int t = threadIdx.x;
#pragma unroll
  for (int i = 0; i < 8; ++i) zs[i*256 + t] = z[i*256 + t];
  __syncthreads();
  int lane = t & 63, bg = t >> 6;
  int b0 = bg*4;
  int idx0 = blockIdx.x*128 + lane;           // stream 0: idx0, stream 1: idx0+64
  float acc[4][2];
  float bv0 = gb[idx0], bv1 = gb[idx0 + 64];
#pragma unroll
  for (int bi = 0; bi < 4; ++bi) { acc[bi][0] = bv0; acc[bi][1] = bv1; }

  for (int z0 = 0; z0 < Z_; z0 += 4) {
    float ga[4], gbv[4];
#pragma unroll
    for (int zi = 0; zi < 4; ++zi) {
      ga[zi]  = gw[(size_t)(z0+zi)*IDXN + idx0];
      gbv[zi] = gw[(size_t)(z0+zi)*IDXN + idx0 + 64];
    }
#pragma unroll
    for (int bi = 0; bi < 4; ++bi) {
      f32x4 zq = *reinterpret_cast<const f32x4*>(&zs[(b0+bi)*Z_ + z0]);
      acc[bi][0] = fmaf(zq[0], ga[0], fmaf(zq[1], ga[1], fmaf(zq[2], ga[2], fmaf(zq[3], ga[3], acc[bi][0]))));
      acc[bi][1] = fmaf(zq[0], gbv[0], fmaf(zq[1], gbv[1], fmaf(zq[2], gbv[2], fmaf(zq[3], gbv[3], acc[bi][1]))));
    }
  }
#pragma unroll
  for (int ni = 0; ni < 2; ++ni) {
    int idx = idx0 + ni*64;
    int kw = idx % 3, r1 = idx/3;
    int kh = r1 % 3, r2 = r1/3;
    int ci = r2 & 63, co = r2 >> 6;
    int k = (kh*3 + kw)*C_ + ci;
    int ts = k >> 5, kin = k & 31;
    int lm = (co & 15) | ((kin >> 3) << 4);
    int j = kin & 7, m = co >> 4;
    int base = ((ts*4 + m)*64 + lm)*8 + j;
#pragma unroll
    for (int bi = 0; bi < 4; ++bi)
      wfrag[(size_t)(b0+bi)*(NT*4*64*8) + base] = f2bf(acc[bi][ni]);
  }
}

// ---------------- kernel 2 (fused): per-sample conv as MFMA implicit GEMM
// 512 threads = 8 waves; wave v: row phr=v>>2, px half pw0=((v>>1)&1)*64, co half mt0=(v&1)*2
// K-loop staggered per wave: wave v starts at t = 2v mod 18 (accumulation order-independent).
// Weight fragments prefetched depth-3 in a register ring (compile-time slot indices).
// LDS: xs[4 rows][130 cols][8 chunk-slots][16B]; slot s at col holds chunk s^(col&7)
__global__ __launch_bounds__(512, 4) void conv_k(
    const float* __restrict__ x,
    const unsigned short* __restrict__ wfrag,
    float* __restrict__ out) {
  __shared__ __align__(16) unsigned char xs[4*130*128];   // 66560 B -> 2 blocks/CU, 16 waves
  int orig = blockIdx.x;
  int blk = (orig & 7)*128 + (orig >> 3);   // bijective XCD swizzle: 1024 = 8*128
  int b = blk >> 6;
  int h0 = (blk & 63)*2;
  int tid = threadIdx.x;
  int v = tid >> 6, lane = tid & 63;

  int l15 = lane & 15, lhi = lane >> 4;
  int phr = v >> 2, pw0 = ((v >> 1) & 1)*64;
  int mt0 = (v & 1)*2;                       // co-tile base (co = mt0*16 .. +31)
  int toff = 2*v;                            // per-wave K-phase stagger
  const unsigned short* wb = wfrag + (size_t)b*(NT*4*64*8);

  // ---- weight prefetch ring, depth 3: slots for logical steps s=0,1,2 (global, no LDS dep)
  short8 wfs[3][2];
#pragma unroll
  for (int s0 = 0; s0 < 3; ++s0) {
    int ta = s0 + toff; if (ta >= NT) ta -= NT;
    wfs[s0][0] = *reinterpret_cast<const short8*>(wb + ((ta*4 + mt0 + 0)*64 + lane)*8);
    wfs[s0][1] = *reinterpret_cast<const short8*>(wb + ((ta*4 + mt0 + 1)*64 + lane)*8);
  }

  // ---- stage 4 halo rows (h0-1..h0+2); wave v stages (row v>>1, chunk-half v&1)
  {
    int r = v >> 1, hf = v & 1;
    int hh = h0 - 1 + r;
    bool hv = (hh >= 0) & (hh < H_);
    unsigned char* ldsrow = xs + r*(130*128);
    if (hv) {
      if (lane < 8) {   // zero pad col 0 (hf=0) / col 129 (hf=1)
        int s = hf ? (1032 + lane) : lane;
        uint4 zv; zv.x = 0; zv.y = 0; zv.z = 0; zv.w = 0;
        *reinterpret_cast<uint4*>(ldsrow + s*16) = zv;
      }
      const float* xrow = x + (((size_t)b*C_)*H_ + hh)*W_;   // + ci*(H_*W_) + w
      int w0 = 2*lane, col0 = w0 + 1, col1 = w0 + 2;
      int g = lane >> 3;                                     // chunk rotation
#pragma unroll
      for (int i = 0; i < 4; ++i) {
        int chunk = (hf*4 + i + g) & 7;
        float2 v2[8];
#pragma unroll
        for (int j = 0; j < 8; ++j)
          v2[j] = *reinterpret_cast<const float2*>(xrow + (size_t)(chunk*8 + j)*(H_*W_) + w0);
        uint4 o0, o1;
        unsigned short* s0 = reinterpret_cast<unsigned short*>(&o0);
        unsigned short* s1 = reinterpret_cast<unsigned short*>(&o1);
#pragma unroll
        for (int j = 0; j < 8; ++j) {
          s0[j] = f2bf(v2[j].x);
          s1[j] = f2bf(v2[j].y);
        }
        int a0 = col0*128 + (((chunk ^ col0) & 7) << 4);
        int a1 = col1*128 + (((chunk ^ col1) & 7) << 4);
        *reinterpret_cast<uint4*>(ldsrow + a0) = o0;
        *reinterpret_cast<uint4*>(ldsrow + a1) = o1;
      }
    } else {
      uint4 zv; zv.x = 0; zv.y = 0; zv.z = 0; zv.w = 0;
#pragma unroll
      for (int it = 0; it < 9; ++it) {   // zero half the row: 520 slots each
        int di = it*64 + lane;
        if (di < 520) *reinterpret_cast<uint4*>(ldsrow + (hf*520 + di)*16) = zv;
      }
    }
  }
  __syncthreads();

  f32x4 acc[4][2];   // [pixel tile][co tile]
#pragma unroll
  for (int mp = 0; mp < 4; ++mp)
#pragma unroll
    for (int nc = 0; nc < 2; ++nc)
      acc[mp][nc] = (f32x4){0.f, 0.f, 0.f, 0.f};

  // ---- A-fragment double buffer; load logical step 0
  short8 xab[2][4];
  {
    int ta = toff; if (ta >= NT) ta -= NT;
    int kk = ta >> 1; int kh = (kk*11) >> 5; int kw = kk - 3*kh; int hf2 = ta & 1;
    int chunk = hf2*4 + lhi;
    int rbase = (phr + kh)*130;
#pragma unroll
    for (int mp = 0; mp < 4; ++mp) {
      int col = pw0 + mp*16 + l15 + kw;
      xab[0][mp] = *reinterpret_cast<const short8*>(&xs[(rbase + col)*128 + (((chunk ^ col) & 7) << 4)]);
    }
  }

#pragma unroll
  for (int s = 0; s < NT; ++s) {
    if (s + 1 < NT) {                      // prefetch next A fragments (LDS)
      int ta = s + 1 + toff; if (ta >= NT) ta -= NT;
      int kk = ta >> 1; int kh = (kk*11) >> 5; int kw = kk - 3*kh; int hf2 = ta & 1;
      int chunk = hf2*4 + lhi;
      int rbase = (phr + kh)*130;
#pragma unroll
      for (int mp = 0; mp < 4; ++mp) {
        int col = pw0 + mp*16 + l15 + kw;
        xab[(s+1)&1][mp] = *reinterpret_cast<const short8*>(&xs[(rbase + col)*128 + (((chunk ^ col) & 7) << 4)]);
      }
    }
#pragma unroll
    for (int mp = 0; mp < 4; ++mp) {
      acc[mp][0] = __builtin_amdgcn_mfma_f32_16x16x32_bf16(xab[s&1][mp], wfs[s%3][0], acc[mp][0], 0, 0, 0);
      acc[mp][1] = __builtin_amdgcn_mfma_f32_16x16x32_bf16(xab[s&1][mp], wfs[s%3][1], acc[mp][1], 0, 0, 0);
    }
    if (s + 3 < NT) {                      // refill weight ring slot (in flight ~2 iters)
      int ta = s + 3 + toff; if (ta >= NT) ta -= NT;
      wfs[s%3][0] = *reinterpret_cast<const short8*>(wb + ((ta*4 + mt0 + 0)*64 + lane)*8);
      wfs[s%3][1] = *reinterpret_cast<const short8*>(wb + ((ta*4 + mt0 + 1)*64 + lane)*8);
    }
  }

  // ---- epilogue: D row=(lane>>4)*4+i -> pixel (contiguous f32x4), col=lane&15 -> co
  int ph = h0 + phr;
#pragma unroll
  for (int nc = 0; nc < 2; ++nc) {
    int co = (mt0 + nc)*16 + l15;
    float* op = out + (((size_t)b*C_ + co)*H_ + ph)*W_;
#pragma unroll
    for (int mp = 0; mp < 4; ++mp) {
      int pix = pw0 + mp*16 + lhi*4;
      *reinterpret_cast<f32x4*>(op + pix) = acc[mp][nc];
    }
  }
}

__global__ void sentinel_k(float* out, int n) {
  int i = blockIdx.x*256 + threadIdx.x;
  if (i < n) out[i] = 1.0e6f;
}

extern "C" void kernel_launch(void* const* d_in, const int* in_sizes, int n_in,
                              void* d_out, int out_size, void* d_ws, size_t ws_size,
                              hipStream_t stream) {
  const float* x  = (const float*)d_in[0];
  const float* z  = (const float*)d_in[1];
  const float* gw = (const float*)d_in[2];
  const float* gb = (const float*)d_in[3];
  float* out = (float*)d_out;

  size_t wfrag_elems = (size_t)B_*IDXN;                   // bf16 elems
  size_t need = wfrag_elems*sizeof(unsigned short);
  if (ws_size < need) {
    sentinel_k<<<(out_size + 255)/256, 256, 0, stream>>>(out, out_size);
    return;
  }
  unsigned short* wfrag = (unsigned short*)d_ws;

  wgen_k <<<IDXN/128, 256, 0, stream>>>(z, gw, gb, wfrag);
  conv_k <<<B_*(H_/2), 512, 0, stream>>>(x, wfrag, out);
}

// Round 8
// 52.426 us; speedup vs baseline: 2.7963x; 1.0004x over previous
//
#include <hip/hip_runtime.h>
#include <hip/hip_bf16.h>

typedef __attribute__((ext_vector_type(4))) float f32x4;
typedef __attribute__((ext_vector_type(8))) short short8;

#define B_ 16
#define C_ 64
#define H_ 128
#define W_ 128
#define Z_ 128
#define HW_ (H_*W_)
#define IDXN (C_*C_*9)    // 36864 weight elements per sample
#define NT 18             // K=576 -> 18 MFMA k-steps of 32

__device__ __forceinline__ unsigned short f2bf(float f) {
  __hip_bfloat16 h = __float2bfloat16(f);
  return *reinterpret_cast<unsigned short*>(&h);
}

// ---------------- kernel 1: weight generation, pre-swizzled to MFMA fragment layout
__global__ __launch_bounds__(256) void wgen_k(
    const float* __restrict__ z, const float* __restrict__ gw,
    const float* __restrict__ gb, unsigned short* __restrict__ wfrag) {
  __shared__ __align__(16) float zs[B_*Z_];   // 8 KB
  int t = threadIdx.x;
#pragma unroll
  for (int i = 0; i < 8; ++i) zs[i*256 + t] = z[i*256 + t];
  __syncthreads();
  int lane = t & 63, bg = t >> 6;
  int b0 = bg*4;
  int idx0 = blockIdx.x*128 + lane;           // stream 0: idx0, stream 1: idx0+64
  float acc[4][2];
  float bv0 = gb[idx0], bv1 = gb[idx0 + 64];
#pragma unroll
  for (int bi = 0; bi < 4; ++bi) { acc[bi][0] = bv0; acc[bi][1] = bv1; }

  for (int z0 = 0; z0 < Z_; z0 += 4) {
    float ga[4], gbv[4];
#pragma unroll
    for (int zi = 0; zi < 4; ++zi) {
      ga[zi]  = gw[(size_t)(z0+zi)*IDXN + idx0];
      gbv[zi] = gw[(size_t)(z0+zi)*IDXN + idx0 + 64];
    }
#pragma unroll
    for (int bi = 0; bi < 4; ++bi) {
      f32x4 zq = *reinterpret_cast<const f32x4*>(&zs[(b0+bi)*Z_ + z0]);
      acc[bi][0] = fmaf(zq[0], ga[0], fmaf(zq[1], ga[1], fmaf(zq[2], ga[2], fmaf(zq[3], ga[3], acc[bi][0]))));
      acc[bi][1] = fmaf(zq[0], gbv[0], fmaf(zq[1], gbv[1], fmaf(zq[2], gbv[2], fmaf(zq[3], gbv[3], acc[bi][1]))));
    }
  }
#pragma unroll
  for (int ni = 0; ni < 2; ++ni) {
    int idx = idx0 + ni*64;
    int kw = idx % 3, r1 = idx/3;
    int kh = r1 % 3, r2 = r1/3;
    int ci = r2 & 63, co = r2 >> 6;
    int k = (kh*3 + kw)*C_ + ci;
    int ts = k >> 5, kin = k & 31;
    int lm = (co & 15) | ((kin >> 3) << 4);
    int j = kin & 7, m = co >> 4;
    int base = ((ts*4 + m)*64 + lm)*8 + j;
#pragma unroll
    for (int bi = 0; bi < 4; ++bi)
      wfrag[(size_t)(b0+bi)*(NT*4*64*8) + base] = f2bf(acc[bi][ni]);
  }
}

// ---------------- kernel 2 (fused): per-sample conv as MFMA implicit GEMM
// Block: sample b, 4 output rows (h0..h0+3). 512 thr = 8 waves.
// Wave v: output row orow=v>>1, px half pw0=(v&1)*64, ALL 64 co (nc=4).
//   -> per K-step: 4 ds_read_b128 + 4 weight b128 loads + 16 MFMA (2x better ratios than 2-row block)
//   -> all 8 waves read the SAME weight tiles each step: intra-block L1 broadcast reuse.
// LDS: xs[6 rows][130 cols][8 chunk-slots][16B]; slot s at col holds ci-chunk s^(col&7).
__global__ __launch_bounds__(512, 2) void conv_k(
    const float* __restrict__ x,
    const unsigned short* __restrict__ wfrag,
    float* __restrict__ out) {
  __shared__ __align__(16) unsigned char xs[6*130*128];   // 99840 B -> 1 block/CU
  int orig = blockIdx.x;
  int blk = (orig & 7)*64 + (orig >> 3);   // bijective XCD swizzle: 512 = 8*64
  int b = blk >> 5;
  int h0 = (blk & 31)*4;
  int tid = threadIdx.x;
  int v = tid >> 6, lane = tid & 63;

  // ---- zero pad cols 0 and 129 of all 6 rows (96 threads, one uint4 each)
  if (tid < 96) {
    int sl = tid >> 4, cc = (tid >> 3) & 1, ch = tid & 7;
    int col = cc ? 129 : 0;
    uint4 zv; zv.x = 0; zv.y = 0; zv.z = 0; zv.w = 0;
    *reinterpret_cast<uint4*>(&xs[(sl*130 + col)*128 + ch*16]) = zv;
  }

  // ---- stage 6 rows (img h0-1 .. h0+4); wave v<6 stages row v (R4-verified pattern)
  if (v < 6) {
    int hh = h0 - 1 + v;
    bool hv = (hh >= 0) & (hh < H_);
    unsigned char* ldsrow = xs + v*(130*128);
    if (hv) {
      const float* xrow = x + (((size_t)b*C_)*H_ + hh)*W_;   // + ci*HW_ + w
      int w0 = 2*lane, col0 = w0 + 1, col1 = w0 + 2;
      int g = lane >> 3;                                     // chunk rotation
#pragma unroll
      for (int i = 0; i < 8; ++i) {
        int chunk = (i + g) & 7;
        float2 v2[8];
#pragma unroll
        for (int j = 0; j < 8; ++j)
          v2[j] = *reinterpret_cast<const float2*>(xrow + (size_t)(chunk*8 + j)*HW_ + w0);
        uint4 o0, o1;
        unsigned short* s0 = reinterpret_cast<unsigned short*>(&o0);
        unsigned short* s1 = reinterpret_cast<unsigned short*>(&o1);
#pragma unroll
        for (int j = 0; j < 8; ++j) { s0[j] = f2bf(v2[j].x); s1[j] = f2bf(v2[j].y); }
        int a0 = col0*128 + (((chunk ^ col0) & 7) << 4);
        int a1 = col1*128 + (((chunk ^ col1) & 7) << 4);
        *reinterpret_cast<uint4*>(ldsrow + a0) = o0;
        *reinterpret_cast<uint4*>(ldsrow + a1) = o1;
      }
    } else {
      uint4 zv; zv.x = 0; zv.y = 0; zv.z = 0; zv.w = 0;
#pragma unroll
      for (int it = 0; it < 17; ++it) {
        int di = it*64 + lane;
        if (di < 1040) *reinterpret_cast<uint4*>(ldsrow + di*16) = zv;
      }
    }
  }
  __syncthreads();

  int l15 = lane & 15, lhi = lane >> 4;
  int orow = v >> 1, pw0 = (v & 1)*64;
  const unsigned short* wb = wfrag + (size_t)b*(NT*4*64*8);

  f32x4 acc[4][4];   // [pixel tile mp][co tile nc]
#pragma unroll
  for (int mp = 0; mp < 4; ++mp)
#pragma unroll
    for (int nc = 0; nc < 4; ++nc)
      acc[mp][nc] = (f32x4){0.f, 0.f, 0.f, 0.f};

  // ---- prefetch t=0 operands (kh=0, kw=0, half=0)
  short8 xa0[4], xa1[4], wf0[4], wf1[4];
  {
    int chunk = lhi;
    int rbase = orow*130;
#pragma unroll
    for (int mp = 0; mp < 4; ++mp) {
      int col = pw0 + mp*16 + l15;
      xa0[mp] = *reinterpret_cast<const short8*>(&xs[(rbase + col)*128 + (((chunk ^ col) & 7) << 4)]);
    }
#pragma unroll
    for (int nc = 0; nc < 4; ++nc)
      wf0[nc] = *reinterpret_cast<const short8*>(wb + ((size_t)(nc*64 + lane))*8);
  }

#pragma unroll
  for (int t = 0; t < NT; ++t) {
    if (t + 1 < NT) {                      // prefetch t+1 (weights first: longest latency)
      int t1 = t + 1;
      int kk = t1 >> 1, kh = kk/3, kw = kk - 3*kh, half = t1 & 1;
      int chunk = half*4 + lhi;
      int rbase = (orow + kh)*130;
#pragma unroll
      for (int nc = 0; nc < 4; ++nc)
        wf1[nc] = *reinterpret_cast<const short8*>(wb + ((size_t)((t1*4 + nc)*64 + lane))*8);
#pragma unroll
      for (int mp = 0; mp < 4; ++mp) {
        int col = pw0 + mp*16 + l15 + kw;
        xa1[mp] = *reinterpret_cast<const short8*>(&xs[(rbase + col)*128 + (((chunk ^ col) & 7) << 4)]);
      }
    }
#pragma unroll
    for (int mp = 0; mp < 4; ++mp)
#pragma unroll
      for (int nc = 0; nc < 4; ++nc)
        acc[mp][nc] = __builtin_amdgcn_mfma_f32_16x16x32_bf16(xa0[mp], wf0[nc], acc[mp][nc], 0, 0, 0);
#pragma unroll
    for (int q = 0; q < 4; ++q) { xa0[q] = xa1[q]; wf0[q] = wf1[q]; }
  }

  // ---- epilogue: D row=(lane>>4)*4+i -> pixel (contiguous f32x4), col=lane&15 -> co
  int ph = h0 + orow;
#pragma unroll
  for (int nc = 0; nc < 4; ++nc) {
    int co = nc*16 + l15;
    float* op = out + (((size_t)b*C_ + co)*H_ + ph)*W_;
#pragma unroll
    for (int mp = 0; mp < 4; ++mp) {
      int pix = pw0 + mp*16 + lhi*4;
      *reinterpret_cast<f32x4*>(op + pix) = acc[mp][nc];
    }
  }
}

__global__ void sentinel_k(float* out, int n) {
  int i = blockIdx.x*256 + threadIdx.x;
  if (i < n) out[i] = 1.0e6f;
}

extern "C" void kernel_launch(void* const* d_in, const int* in_sizes, int n_in,
                              void* d_out, int out_size, void* d_ws, size_t ws_size,
                              hipStream_t stream) {
  const float* x  = (const float*)d_in[0];
  const float* z  = (const float*)d_in[1];
  const float* gw = (const float*)d_in[2];
  const float* gb = (const float*)d_in[3];
  float* out = (float*)d_out;

  size_t wfrag_elems = (size_t)B_*IDXN;                   // bf16 elems
  size_t need = wfrag_elems*sizeof(unsigned short);
  if (ws_size < need) {
    sentinel_k<<<(out_size + 255)/256, 256, 0, stream>>>(out, out_size);
    return;
  }
  unsigned short* wfrag = (unsigned short*)d_ws;

  wgen_k <<<IDXN/128, 256, 0, stream>>>(z, gw, gb, wfrag);
  conv_k <<<B_*(H_/4), 512, 0, stream>>>(x, wfrag, out);
}